// Round 4
// baseline (352.158 us; speedup 1.0000x reference)
//
#include <hip/hip_runtime.h>
#include <math.h>

#define NKV    8
#define NREP   4
#define NH     32
#define BATCH  8
#define D      128
#define SEQ    4096
#define CHUNKS 32
#define CS     128          // SEQ / CHUNKS
#define PSTRIDE 130         // 128 o + m + l per (pair,chunk,rep)
#define WS_PART_FLOATS ((size_t)64 * CHUNKS * NREP * PSTRIDE)

// ---------------------------------------------------------------------------
// Fused kernel: partial attention per (pair = g*8+b, chunk) + last-block
// per-pair LSE combine. grid (64, CHUNKS), block 256 (4 waves).
// Phase 1: wave w owns rows [w*32, w*32+32), computes ALL 4 reps (K read once).
// __launch_bounds__(256,4): 128-VGPR budget so qv[4][4] + hoisted loads fit.
// ---------------------------------------------------------------------------
__global__ __launch_bounds__(256, 4) void attn_fused(
    const int*   __restrict__ input_pos,
    const float* __restrict__ q,
    const float* __restrict__ knew,
    const float* __restrict__ vnew,
    const float* __restrict__ kcache,
    const float* __restrict__ vcache,
    const float* __restrict__ mask,
    float*       __restrict__ ws,
    int*         __restrict__ cnt,
    float*       __restrict__ out)
{
    const int pair = blockIdx.x;      // g*8 + b
    const int c    = blockIdx.y;
    const int g    = pair >> 3;
    const int b    = pair & 7;
    const int t    = threadIdx.x;
    const int w    = t >> 6;          // wave id
    const int lane = t & 63;
    const int p8   = lane >> 3;       // row within 8-row group
    const int l8   = lane & 7;        // 16-float segment of the row
    const int pos  = input_pos[0];

    __shared__ float sc[NREP][CS];        // raw scores, then e-values
    __shared__ float ml[NREP][2];         // per-rep (max, sum)
    __shared__ float opart[4][NREP][D];   // per-wave PV partials (8 KiB)
    __shared__ int   is_last;

    const float  scale  = 0.08838834764831845f;   // 1/sqrt(128)
    const size_t kvbase = (size_t)(g * BATCH + b) * SEQ * D;
    const float* kbase  = kcache + kvbase;
    const float* vbase  = vcache + kvbase;
    const float* mrow   = mask + (size_t)pos * SEQ;
    const float* knewr  = knew + (size_t)(g * BATCH + b) * D;
    const float* vnewr  = vnew + (size_t)(g * BATCH + b) * D;
    const int    s0     = c * CS;

    // ---- phase 1: q fragments for all 4 reps (16 floats each = 64 VGPRs) ----
    float4 qv[NREP][4];
    #pragma unroll
    for (int r = 0; r < NREP; ++r) {
        const float4* qr = (const float4*)(q + ((size_t)(g * NREP + r) * BATCH + b) * D
                                           + l8 * 16);
        #pragma unroll
        for (int j = 0; j < 4; ++j) qv[r][j] = qr[j];
    }

    const int rowbase = w * 32;
    #pragma unroll
    for (int i = 0; i < 4; ++i) {
        const int sl = rowbase + i * 8 + p8;
        const int s  = s0 + sl;
        const float* krow = (s == pos) ? knewr : (kbase + (size_t)s * D);
        const float4* k4  = (const float4*)(krow + l8 * 16);
        float4 kb[4];
        #pragma unroll
        for (int j = 0; j < 4; ++j) kb[j] = k4[j];
        const float mval = mrow[s];

        float acc[NREP] = {0.f, 0.f, 0.f, 0.f};
        #pragma unroll
        for (int r = 0; r < NREP; ++r) {
            #pragma unroll
            for (int j = 0; j < 4; ++j) {
                acc[r] = fmaf(kb[j].x, qv[r][j].x, acc[r]);
                acc[r] = fmaf(kb[j].y, qv[r][j].y, acc[r]);
                acc[r] = fmaf(kb[j].z, qv[r][j].z, acc[r]);
                acc[r] = fmaf(kb[j].w, qv[r][j].w, acc[r]);
            }
        }
        // reduce across the 8 segment lanes (3 rounds)
        #pragma unroll
        for (int off = 1; off < 8; off <<= 1) {
            #pragma unroll
            for (int r = 0; r < NREP; ++r)
                acc[r] += __shfl_xor(acc[r], off);
        }
        if (l8 == 0) {
            #pragma unroll
            for (int r = 0; r < NREP; ++r)
                sc[r][sl] = acc[r] * scale + mval;
        }
    }
    __syncthreads();

    // ---- phase 1.5: per-rep softmax (wave w owns rep r = w) ----
    {
        const int r = w;
        float v0 = sc[r][lane];
        float v1 = sc[r][lane + 64];
        float m  = fmaxf(v0, v1);
        #pragma unroll
        for (int off = 1; off < 64; off <<= 1)
            m = fmaxf(m, __shfl_xor(m, off));
        float e0 = __expf(v0 - m);
        float e1 = __expf(v1 - m);
        sc[r][lane]      = e0;
        sc[r][lane + 64] = e1;
        float l = e0 + e1;
        #pragma unroll
        for (int off = 1; off < 64; off <<= 1)
            l += __shfl_xor(l, off);
        if (lane == 0) { ml[r][0] = m; ml[r][1] = l; }
    }
    __syncthreads();

    // ---- phase 2: PV. wave w owns rows [w*32, w*32+32); V read once, float4 ----
    const int half = lane >> 5;
    const int l32  = lane & 31;
    float4 oacc[NREP];
    #pragma unroll
    for (int r = 0; r < NREP; ++r) oacc[r] = make_float4(0.f, 0.f, 0.f, 0.f);

    #pragma unroll
    for (int it = 0; it < 16; ++it) {
        int sl = w * 32 + it * 2 + half;
        int s  = s0 + sl;
        const float* vrow = (s == pos) ? vnewr : (vbase + (size_t)s * D);
        float4 vv = *(const float4*)(vrow + l32 * 4);
        #pragma unroll
        for (int r = 0; r < NREP; ++r) {
            float pr = sc[r][sl];
            oacc[r].x = fmaf(pr, vv.x, oacc[r].x);
            oacc[r].y = fmaf(pr, vv.y, oacc[r].y);
            oacc[r].z = fmaf(pr, vv.z, oacc[r].z);
            oacc[r].w = fmaf(pr, vv.w, oacc[r].w);
        }
    }
    #pragma unroll
    for (int r = 0; r < NREP; ++r) {
        oacc[r].x += __shfl_xor(oacc[r].x, 32);
        oacc[r].y += __shfl_xor(oacc[r].y, 32);
        oacc[r].z += __shfl_xor(oacc[r].z, 32);
        oacc[r].w += __shfl_xor(oacc[r].w, 32);
    }
    if (half == 0) {
        #pragma unroll
        for (int r = 0; r < NREP; ++r)
            *(float4*)&opart[w][r][l32 * 4] = oacc[r];
    }
    __syncthreads();

    // ---- write this chunk's partials to ws ----
    #pragma unroll
    for (int ii = 0; ii < 2; ++ii) {
        int idx = t + ii * 256;       // 0..511 -> (r, d)
        int r   = idx >> 7;
        int d   = idx & 127;
        float sum = opart[0][r][d] + opart[1][r][d]
                  + opart[2][r][d] + opart[3][r][d];
        size_t base = (((size_t)pair * CHUNKS + c) * NREP + r) * PSTRIDE;
        ws[base + d] = sum;
        if (d == 0) { ws[base + 128] = ml[r][0]; ws[base + 129] = ml[r][1]; }
    }

    // ---- arrive; last block for this pair does the LSE combine ----
    __threadfence();                  // release ws writes (device scope)
    if (t == 0) {
        int old = atomicAdd(&cnt[pair], 1);
        is_last = (old == CHUNKS - 1);
    }
    __syncthreads();
    if (!is_last) return;
    __threadfence();                  // acquire other blocks' ws writes

    #pragma unroll
    for (int ii = 0; ii < 2; ++ii) {
        int idx = t + ii * 256;       // (r, d)
        int r   = idx >> 7;
        int d   = idx & 127;
        size_t base0 = (((size_t)pair * CHUNKS) * NREP + r) * PSTRIDE;
        const size_t cstep = (size_t)NREP * PSTRIDE;

        float M = -INFINITY;
        for (int cc = 0; cc < CHUNKS; ++cc)
            M = fmaxf(M, ws[base0 + cc * cstep + 128]);
        float acc = 0.f, L = 0.f;
        for (int cc = 0; cc < CHUNKS; ++cc) {
            size_t base = base0 + cc * cstep;
            float wgt = __expf(ws[base + 128] - M);
            acc += ws[base + d] * wgt;
            L   += ws[base + 129] * wgt;
        }
        int h = g * NREP + r;
        out[(size_t)b * (NH * D) + h * D + d] = acc / L;
    }
}

// ---------------------------------------------------------------------------
// Fallback (ws too small): one block per (head, batch), full sequence.
// grid 256, block 256.
// ---------------------------------------------------------------------------
__global__ __launch_bounds__(256) void attn_full(
    const int*   __restrict__ input_pos,
    const float* __restrict__ q,
    const float* __restrict__ knew,
    const float* __restrict__ vnew,
    const float* __restrict__ kcache,
    const float* __restrict__ vcache,
    const float* __restrict__ mask,
    float*       __restrict__ out)
{
    const int idx = blockIdx.x;       // h*8 + b
    const int h   = idx >> 3;
    const int b   = idx & 7;
    const int g   = h >> 2;
    const int t   = threadIdx.x;
    const int wave = t >> 6, lane = t & 63, half = lane >> 5, l32 = lane & 31;
    const int pos = input_pos[0];

    __shared__ float sc[SEQ];         // 16 KB
    __shared__ float wred[4];
    __shared__ float oacc[2][D];

    const size_t kvbase = (size_t)(g * BATCH + b) * SEQ * D;
    const float* kbase  = kcache + kvbase;
    const float* vbase  = vcache + kvbase;
    const float* mrow   = mask + (size_t)pos * SEQ;
    const float* knewr  = knew + (size_t)(g * BATCH + b) * D;
    const float* vnewr  = vnew + (size_t)(g * BATCH + b) * D;
    const float  scale  = 0.08838834764831845f;

    float4 qv = ((const float4*)(q + (size_t)(h * BATCH + b) * D))[l32];

    for (int p = 0; p < SEQ / 8; ++p) {
        int s = p * 8 + wave * 2 + half;
        const float4* krow = (s == pos) ? (const float4*)knewr
                                        : (const float4*)(kbase + (size_t)s * D);
        float4 kv = krow[l32];
        float acc = qv.x * kv.x + qv.y * kv.y + qv.z * kv.z + qv.w * kv.w;
        #pragma unroll
        for (int off = 1; off < 32; off <<= 1)
            acc += __shfl_xor(acc, off);
        if (l32 == 0) sc[s] = acc * scale + mrow[s];
    }
    __syncthreads();

    float m = -INFINITY;
    for (int s = t; s < SEQ; s += 256) m = fmaxf(m, sc[s]);
    #pragma unroll
    for (int off = 1; off < 64; off <<= 1) m = fmaxf(m, __shfl_xor(m, off));
    if (lane == 0) wred[wave] = m;
    __syncthreads();
    m = fmaxf(fmaxf(wred[0], wred[1]), fmaxf(wred[2], wred[3]));
    __syncthreads();

    float l = 0.f;
    for (int s = t; s < SEQ; s += 256) { float e = __expf(sc[s] - m); sc[s] = e; l += e; }
    #pragma unroll
    for (int off = 1; off < 64; off <<= 1) l += __shfl_xor(l, off);
    __syncthreads();
    if (lane == 0) wred[wave] = l;
    __syncthreads();
    float L = wred[0] + wred[1] + wred[2] + wred[3];

    {
        int hf = t >> 7, d = t & 127;
        float acc = 0.f;
        for (int s = hf * (SEQ / 2); s < (hf + 1) * (SEQ / 2); ++s) {
            const float* vrow = (s == pos) ? vnewr : (vbase + (size_t)s * D);
            acc += sc[s] * vrow[d];
        }
        oacc[hf][d] = acc;
    }
    __syncthreads();
    if (t < D) out[(size_t)b * (NH * D) + h * D + t] = (oacc[0][t] + oacc[1][t]) / L;
}

extern "C" void kernel_launch(void* const* d_in, const int* in_sizes, int n_in,
                              void* d_out, int out_size, void* d_ws, size_t ws_size,
                              hipStream_t stream) {
    const int*   input_pos = (const int*)  d_in[0];
    const float* q         = (const float*)d_in[1];
    const float* k         = (const float*)d_in[2];
    const float* v         = (const float*)d_in[3];
    const float* kcache    = (const float*)d_in[4];
    const float* vcache    = (const float*)d_in[5];
    const float* mask      = (const float*)d_in[6];
    float* out = (float*)d_out;

    const size_t part_bytes = WS_PART_FLOATS * sizeof(float);
    const size_t need       = part_bytes + 64 * sizeof(int);
    if (ws_size >= need) {
        int* cnt = (int*)((char*)d_ws + part_bytes);
        hipMemsetAsync(cnt, 0, 64 * sizeof(int), stream);
        dim3 g1(64, CHUNKS);
        attn_fused<<<g1, 256, 0, stream>>>(input_pos, q, k, v, kcache, vcache, mask,
                                           (float*)d_ws, cnt, out);
    } else {
        attn_full<<<256, 256, 0, stream>>>(input_pos, q, k, v, kcache, vcache, mask, out);
    }
}

// Round 5
// 51.847 us; speedup vs baseline: 6.7923x; 6.7923x over previous
//
#include <hip/hip_runtime.h>
#include <math.h>

#define NKV    8
#define NREP   4
#define NH     32
#define BATCH  8
#define D      128
#define SEQ    4096
#define CHUNKS 32
#define CS     128          // SEQ / CHUNKS
#define PSTRIDE 130         // 128 o + m + l per (pair,chunk,rep)

// ---------------------------------------------------------------------------
// Kernel 1: partial attention per (pair = g*8+b, chunk).
// grid (64, CHUNKS), block 256 (4 waves), __launch_bounds__(256,4) -> 128 VGPR.
// Phase 1: wave w owns rows [w*32, w*32+32), computes ALL 4 reps (K read once).
//   Lane split: p4 = lane>>4 (4 rows/instr), l16 = lane&15 (8-float segment).
//   ALL 16 K float4 loads hoisted into registers before the FMAs.
// V for phase 2 is loaded into registers BEFORE the softmax barrier so its
// latency hides under softmax.
// ---------------------------------------------------------------------------
__global__ __launch_bounds__(256, 4) void attn_partial(
    const int*   __restrict__ input_pos,
    const float* __restrict__ q,
    const float* __restrict__ knew,
    const float* __restrict__ vnew,
    const float* __restrict__ kcache,
    const float* __restrict__ vcache,
    const float* __restrict__ mask,
    float*       __restrict__ ws)
{
    const int pair = blockIdx.x;      // g*8 + b
    const int c    = blockIdx.y;
    const int g    = pair >> 3;
    const int b    = pair & 7;
    const int t    = threadIdx.x;
    const int w    = t >> 6;          // wave id
    const int lane = t & 63;
    const int p4   = lane >> 4;       // row within 4-row group (0..3)
    const int l16  = lane & 15;       // 8-float segment of the row (0..15)
    const int pos  = input_pos[0];

    __shared__ float sc[NREP][CS];        // raw scores, then e-values
    __shared__ float ml[NREP][2];         // per-rep (max, sum)
    __shared__ float opart[4][NREP][D];   // per-wave PV partials (8 KiB)

    const float  scale  = 0.08838834764831845f;   // 1/sqrt(128)
    const size_t kvbase = (size_t)(g * BATCH + b) * SEQ * D;
    const float* kbase  = kcache + kvbase;
    const float* vbase  = vcache + kvbase;
    const float* mrow   = mask + (size_t)pos * SEQ;
    const float* knewr  = knew + (size_t)(g * BATCH + b) * D;
    const float* vnewr  = vnew + (size_t)(g * BATCH + b) * D;
    const int    s0     = c * CS;
    const int    rowbase = w * 32;

    // ---- phase 1a: q fragments for all 4 reps (8 floats each = 32 VGPRs) ----
    float4 qv[NREP][2];
    #pragma unroll
    for (int r = 0; r < NREP; ++r) {
        const float4* qr = (const float4*)(q + ((size_t)(g * NREP + r) * BATCH + b) * D
                                           + l16 * 8);
        qv[r][0] = qr[0];
        qv[r][1] = qr[1];
    }

    // ---- phase 1b: hoist ALL K loads (8 iters x 2 float4 = 64 VGPRs) ----
    float4 kb[8][2];
    #pragma unroll
    for (int i = 0; i < 8; ++i) {
        const int s = s0 + rowbase + i * 4 + p4;
        const float* krow = (s == pos) ? knewr : (kbase + (size_t)s * D);
        const float4* k4  = (const float4*)(krow + l16 * 8);
        kb[i][0] = k4[0];
        kb[i][1] = k4[1];
    }

    // ---- phase 1c: dot products + 4-round butterfly reduce over l16 ----
    #pragma unroll
    for (int i = 0; i < 8; ++i) {
        const int sl = rowbase + i * 4 + p4;
        float acc[NREP];
        #pragma unroll
        for (int r = 0; r < NREP; ++r) {
            float a;
            a = kb[i][0].x * qv[r][0].x;
            a = fmaf(kb[i][0].y, qv[r][0].y, a);
            a = fmaf(kb[i][0].z, qv[r][0].z, a);
            a = fmaf(kb[i][0].w, qv[r][0].w, a);
            a = fmaf(kb[i][1].x, qv[r][1].x, a);
            a = fmaf(kb[i][1].y, qv[r][1].y, a);
            a = fmaf(kb[i][1].z, qv[r][1].z, a);
            a = fmaf(kb[i][1].w, qv[r][1].w, a);
            acc[r] = a;
        }
        #pragma unroll
        for (int off = 1; off < 16; off <<= 1) {
            #pragma unroll
            for (int r = 0; r < NREP; ++r)
                acc[r] += __shfl_xor(acc[r], off);
        }
        if (l16 == 0) {
            const float mval = mrow[s0 + sl];
            #pragma unroll
            for (int r = 0; r < NREP; ++r)
                sc[r][sl] = acc[r] * scale + mval;
        }
    }
    __syncthreads();

    // ---- phase 2a: issue ALL V loads now (latency hides under softmax) ----
    const int half = lane >> 5;
    const int l32  = lane & 31;
    float4 vv[16];
    #pragma unroll
    for (int it = 0; it < 16; ++it) {
        const int s = s0 + rowbase + it * 2 + half;
        const float* vrow = (s == pos) ? vnewr : (vbase + (size_t)s * D);
        vv[it] = *(const float4*)(vrow + l32 * 4);
    }

    // ---- phase 1.5: per-rep softmax (wave w owns rep r = w) ----
    {
        const int r = w;
        float v0 = sc[r][lane];
        float v1 = sc[r][lane + 64];
        float m  = fmaxf(v0, v1);
        #pragma unroll
        for (int off = 1; off < 64; off <<= 1)
            m = fmaxf(m, __shfl_xor(m, off));
        float e0 = __expf(v0 - m);
        float e1 = __expf(v1 - m);
        sc[r][lane]      = e0;
        sc[r][lane + 64] = e1;
        float l = e0 + e1;
        #pragma unroll
        for (int off = 1; off < 64; off <<= 1)
            l += __shfl_xor(l, off);
        if (lane == 0) { ml[r][0] = m; ml[r][1] = l; }
    }
    __syncthreads();

    // ---- phase 2b: PV from registers ----
    float4 oacc[NREP];
    #pragma unroll
    for (int r = 0; r < NREP; ++r) oacc[r] = make_float4(0.f, 0.f, 0.f, 0.f);

    #pragma unroll
    for (int it = 0; it < 16; ++it) {
        const int sl = rowbase + it * 2 + half;
        const float4 v4 = vv[it];
        #pragma unroll
        for (int r = 0; r < NREP; ++r) {
            const float pr = sc[r][sl];
            oacc[r].x = fmaf(pr, v4.x, oacc[r].x);
            oacc[r].y = fmaf(pr, v4.y, oacc[r].y);
            oacc[r].z = fmaf(pr, v4.z, oacc[r].z);
            oacc[r].w = fmaf(pr, v4.w, oacc[r].w);
        }
    }
    #pragma unroll
    for (int r = 0; r < NREP; ++r) {
        oacc[r].x += __shfl_xor(oacc[r].x, 32);
        oacc[r].y += __shfl_xor(oacc[r].y, 32);
        oacc[r].z += __shfl_xor(oacc[r].z, 32);
        oacc[r].w += __shfl_xor(oacc[r].w, 32);
    }
    if (half == 0) {
        #pragma unroll
        for (int r = 0; r < NREP; ++r)
            *(float4*)&opart[w][r][l32 * 4] = oacc[r];
    }
    __syncthreads();

    // ---- final: sum the 4 wave partials, write workspace ----
    #pragma unroll
    for (int ii = 0; ii < 2; ++ii) {
        int idx = t + ii * 256;       // 0..511 -> (r, d)
        int r   = idx >> 7;
        int d   = idx & 127;
        float sum = opart[0][r][d] + opart[1][r][d]
                  + opart[2][r][d] + opart[3][r][d];
        size_t base = (((size_t)pair * CHUNKS + c) * NREP + r) * PSTRIDE;
        ws[base + d] = sum;
        if (d == 0) { ws[base + 128] = ml[r][0]; ws[base + 129] = ml[r][1]; }
    }
}

// ---------------------------------------------------------------------------
// Kernel 2: LSE-combine the 32 chunks per (pair, rep). grid 256, block 128.
// ---------------------------------------------------------------------------
__global__ __launch_bounds__(128) void attn_reduce(
    const float* __restrict__ ws, float* __restrict__ out)
{
    const int idx  = blockIdx.x;      // (pair, r)
    const int pair = idx >> 2;
    const int r    = idx & 3;
    const int g    = pair >> 3;
    const int b    = pair & 7;
    const int d    = threadIdx.x;

    float mv[CHUNKS], lv[CHUNKS];
    float M = -INFINITY;
    #pragma unroll
    for (int c = 0; c < CHUNKS; ++c) {
        size_t base = (((size_t)pair * CHUNKS + c) * NREP + r) * PSTRIDE;
        float2 t = *(const float2*)&ws[base + 128];
        mv[c] = t.x; lv[c] = t.y;
        M = fmaxf(M, t.x);
    }
    float acc = 0.f, L = 0.f;
    #pragma unroll
    for (int c = 0; c < CHUNKS; ++c) {
        size_t base = (((size_t)pair * CHUNKS + c) * NREP + r) * PSTRIDE;
        float wgt = __expf(mv[c] - M);
        acc += ws[base + d] * wgt;
        L   += lv[c] * wgt;
    }
    int h = g * NREP + r;
    out[(size_t)b * (NH * D) + h * D + d] = acc / L;
}

// ---------------------------------------------------------------------------
// Fallback (ws too small): one block per (head, batch), full sequence.
// grid 256, block 256.
// ---------------------------------------------------------------------------
__global__ __launch_bounds__(256) void attn_full(
    const int*   __restrict__ input_pos,
    const float* __restrict__ q,
    const float* __restrict__ knew,
    const float* __restrict__ vnew,
    const float* __restrict__ kcache,
    const float* __restrict__ vcache,
    const float* __restrict__ mask,
    float*       __restrict__ out)
{
    const int idx = blockIdx.x;       // h*8 + b
    const int h   = idx >> 3;
    const int b   = idx & 7;
    const int g   = h >> 2;
    const int t   = threadIdx.x;
    const int wave = t >> 6, lane = t & 63, half = lane >> 5, l32 = lane & 31;
    const int pos = input_pos[0];

    __shared__ float sc[SEQ];         // 16 KB
    __shared__ float wred[4];
    __shared__ float oacc[2][D];

    const size_t kvbase = (size_t)(g * BATCH + b) * SEQ * D;
    const float* kbase  = kcache + kvbase;
    const float* vbase  = vcache + kvbase;
    const float* mrow   = mask + (size_t)pos * SEQ;
    const float* knewr  = knew + (size_t)(g * BATCH + b) * D;
    const float* vnewr  = vnew + (size_t)(g * BATCH + b) * D;
    const float  scale  = 0.08838834764831845f;

    float4 qv = ((const float4*)(q + (size_t)(h * BATCH + b) * D))[l32];

    for (int p = 0; p < SEQ / 8; ++p) {
        int s = p * 8 + wave * 2 + half;
        const float4* krow = (s == pos) ? (const float4*)knewr
                                        : (const float4*)(kbase + (size_t)s * D);
        float4 kv = krow[l32];
        float acc = qv.x * kv.x + qv.y * kv.y + qv.z * kv.z + qv.w * kv.w;
        #pragma unroll
        for (int off = 1; off < 32; off <<= 1)
            acc += __shfl_xor(acc, off);
        if (l32 == 0) sc[s] = acc * scale + mrow[s];
    }
    __syncthreads();

    float m = -INFINITY;
    for (int s = t; s < SEQ; s += 256) m = fmaxf(m, sc[s]);
    #pragma unroll
    for (int off = 1; off < 64; off <<= 1) m = fmaxf(m, __shfl_xor(m, off));
    if (lane == 0) wred[wave] = m;
    __syncthreads();
    m = fmaxf(fmaxf(wred[0], wred[1]), fmaxf(wred[2], wred[3]));
    __syncthreads();

    float l = 0.f;
    for (int s = t; s < SEQ; s += 256) { float e = __expf(sc[s] - m); sc[s] = e; l += e; }
    #pragma unroll
    for (int off = 1; off < 64; off <<= 1) l += __shfl_xor(l, off);
    __syncthreads();
    if (lane == 0) wred[wave] = l;
    __syncthreads();
    float L = wred[0] + wred[1] + wred[2] + wred[3];

    {
        int hf = t >> 7, d = t & 127;
        float acc = 0.f;
        for (int s = hf * (SEQ / 2); s < (hf + 1) * (SEQ / 2); ++s) {
            const float* vrow = (s == pos) ? vnewr : (vbase + (size_t)s * D);
            acc += sc[s] * vrow[d];
        }
        oacc[hf][d] = acc;
    }
    __syncthreads();
    if (t < D) out[(size_t)b * (NH * D) + h * D + t] = (oacc[0][t] + oacc[1][t]) / L;
}

extern "C" void kernel_launch(void* const* d_in, const int* in_sizes, int n_in,
                              void* d_out, int out_size, void* d_ws, size_t ws_size,
                              hipStream_t stream) {
    const int*   input_pos = (const int*)  d_in[0];
    const float* q         = (const float*)d_in[1];
    const float* k         = (const float*)d_in[2];
    const float* v         = (const float*)d_in[3];
    const float* kcache    = (const float*)d_in[4];
    const float* vcache    = (const float*)d_in[5];
    const float* mask      = (const float*)d_in[6];
    float* out = (float*)d_out;

    const size_t need = (size_t)64 * CHUNKS * NREP * PSTRIDE * sizeof(float);
    if (ws_size >= need) {
        dim3 g1(64, CHUNKS);
        attn_partial<<<g1, 256, 0, stream>>>(input_pos, q, k, v, kcache, vcache, mask,
                                             (float*)d_ws);
        attn_reduce<<<256, 128, 0, stream>>>((const float*)d_ws, out);
    } else {
        attn_full<<<256, 256, 0, stream>>>(input_pos, q, k, v, kcache, vcache, mask, out);
    }
}